// Round 3
// baseline (50.964 us; speedup 1.0000x reference)
//
#include <hip/hip_runtime.h>

#define IMG_H 1024
#define IMG_W 1024

__global__ __launch_bounds__(512, 8) void EdgePreserve_kernel(const float* __restrict__ x,
                                                              float* __restrict__ out) {
    const int t    = threadIdx.x;
    const int half = t >> 8;          // 0: rows 0-7 of strip, 1: rows 8-15
    const int tt   = t & 255;
    const int lane = t & 63;

    const int bid = blockIdx.x;       // b*64 + pool_row
    const int b   = bid >> 6;
    const int pr  = bid & 63;
    const int r0  = (pr << 4) + (half << 3);
    const int c0  = tt << 2;

    // w = exp(-(nb-x0)^2/8) * exp(-dist2/5000) = exp2(d*d*Cc + Ws[dist2])
    const float Cc  = -0.1803368801111244f;    // -(1/8)*log2(e)
    const float Ws1 = -2.8853900817779270e-4f; // log2(exp(-1/5000))
    const float Ws2 = -5.7707801635558540e-4f; // log2(exp(-2/5000))

    const float* base = x + (size_t)b * (IMG_H * IMG_W);

    const bool left_edge  = (c0 == 0);              // only true on lane 0
    const bool right_edge = (c0 + 4 == IMG_W);      // only true on lane 63

    // 4-slot ring of raw rows, prefetch distance = 2 iterations.
    // slot(q) = (q+1) & 3 for relative row q (fully unrolled -> const indices)
    float4 raw[4];
    float  hl[4], hr[4];       // halo scalars for lanes 0 / 63
    float  win[3][6];

    auto issue = [&](int q, int slot) {
        int r  = r0 + q;
        int rr = (r < 0) ? -r : ((r >= IMG_H) ? (2 * IMG_H - 2 - r) : r);
        const float* row = base + rr * IMG_W;
        raw[slot] = *reinterpret_cast<const float4*>(row + c0);
        if (lane == 0  && !left_edge)  hl[slot] = row[c0 - 1];
        if (lane == 63 && !right_edge) hr[slot] = row[c0 + 4];
    };

    auto expand = [&](int slot, float* dst) {
        float4 v = raw[slot];
        float left  = __shfl_up(v.w, 1);
        float right = __shfl_down(v.x, 1);
        if (lane == 0)  left  = left_edge  ? v.y : hl[slot];
        if (lane == 63) right = right_edge ? v.z : hr[slot];
        dst[0] = left;
        dst[1] = v.x; dst[2] = v.y; dst[3] = v.z; dst[4] = v.w;
        dst[5] = right;
    };

    // prologue: rows q=-1,0,1,2 in flight; expand q=-1,0
    issue(-1, 0);
    issue(0, 1);
    issue(1, 2);
    issue(2, 3);
    expand(0, win[0]);    // row r0-1
    expand(1, win[1]);    // row r0

    float psum = 0.0f;

    #pragma unroll
    for (int r = 0; r < 8; ++r) {
        if (r < 6) issue(r + 3, r & 3);          // slot((r+3)) = (r+4)&3 = r&3
        expand((r + 2) & 3, win[(r + 2) % 3]);   // row q=r+1, issued 2 iters ago

        const float* A  = win[r % 3];            // row r-1
        const float* Bw = win[(r + 1) % 3];      // row r
        const float* Cw = win[(r + 2) % 3];      // row r+1

        #pragma unroll
        for (int i = 0; i < 4; ++i) {
            const float x0 = Bw[i + 1];
            float num = x0;       // center: w = 1
            float den = 1.0f;

            auto acc = [&](float nb, float ws) {
                float d = nb - x0;
                float w = __builtin_amdgcn_exp2f(fmaf(d * d, Cc, ws));
                num = fmaf(w, nb, num);
                den += w;
            };

            acc(A[i],     Ws2); acc(A[i + 1], Ws1); acc(A[i + 2], Ws2);
            acc(Bw[i],    Ws1);                     acc(Bw[i + 2], Ws1);
            acc(Cw[i],    Ws2); acc(Cw[i + 1], Ws1); acc(Cw[i + 2], Ws2);

            psum = fmaf(num, __builtin_amdgcn_rcpf(den), psum);
        }
    }

    // 4-lane group shares one pool column
    psum += __shfl_xor(psum, 1);
    psum += __shfl_xor(psum, 2);

    // combine the two 8-row halves via LDS
    __shared__ float red[64];
    if (half == 1 && (tt & 3) == 0) red[tt >> 2] = psum;
    __syncthreads();
    if (half == 0 && (tt & 3) == 0) {
        out[(size_t)bid * 64 + (tt >> 2)] = (psum + red[tt >> 2]) * (1.0f / 256.0f);
    }
}

extern "C" void kernel_launch(void* const* d_in, const int* in_sizes, int n_in,
                              void* d_out, int out_size, void* d_ws, size_t ws_size,
                              hipStream_t stream) {
    const float* x = (const float*)d_in[0];
    float* out     = (float*)d_out;
    EdgePreserve_kernel<<<dim3(16 * 64), dim3(512), 0, stream>>>(x, out);
}

// Round 4
// 33.140 us; speedup vs baseline: 1.5378x; 1.5378x over previous
//
#include <hip/hip_runtime.h>

#define IMG_H 1024
#define IMG_W 1024

__global__ __launch_bounds__(256) void EdgePreserve_kernel(const float* __restrict__ x,
                                                           float* __restrict__ out) {
    const int t   = threadIdx.x;
    const int bid = blockIdx.x;            // ((b*64 + pr)<<1) | ch
    const int ch  = bid & 1;
    const int pr  = (bid >> 1) & 63;
    const int b   = bid >> 7;
    const int r0  = pr << 4;
    const int c0  = (ch << 9) + (t << 1);  // 2 consecutive cols per thread

    // w = exp(-(nb-x0)^2/8) * exp(-dist2/5000) = exp2(d*d*Cc + Ws[dist2])
    const float Cc  = -0.1803368801111244f;    // -(1/8)*log2(e)
    const float Ws1 = -2.8853900817779270e-4f; // log2(exp(-1/5000))
    const float Ws2 = -5.7707801635558540e-4f; // log2(exp(-2/5000))

    const float* base = x + (size_t)b * (IMG_H * IMG_W);

    const int cl = (c0 == 0) ? 1 : c0 - 1;                 // reflect left
    const int cr = (c0 + 2 >= IMG_W) ? IMG_W - 2 : c0 + 2; // reflect right

    // 4 rows of scalar state: A=r-1, B=r, C=r+1, P=prefetch (r+3 in steady state)
    float A0, A1, A2, A3, B0, B1, B2, B3, C0, C1, C2, C3, P0, P1, P2, P3;

#define LOADROW(q, d0, d1, d2, d3)                                              \
    {                                                                           \
        int _r  = r0 + (q);                                                     \
        int _rr = (_r < 0) ? -_r : ((_r >= IMG_H) ? (2 * IMG_H - 2 - _r) : _r); \
        const float* _rp = base + _rr * IMG_W;                                  \
        float2 _v = *reinterpret_cast<const float2*>(_rp + c0);                 \
        d0 = _rp[cl]; d1 = _v.x; d2 = _v.y; d3 = _rp[cr];                       \
    }

    LOADROW(-1, A0, A1, A2, A3)
    LOADROW(0,  B0, B1, B2, B3)
    LOADROW(1,  C0, C1, C2, C3)
    LOADROW(2,  P0, P1, P2, P3)

    float psum = 0.0f;

    #pragma unroll
    for (int r = 0; r < 16; ++r) {
        // ---- pixel 0: center B1, window {A0,A1,A2, B0,B2, C0,C1,C2} ----
        {
            const float x0 = B1;
            float num = x0, den = 1.0f;
            auto acc = [&](float nb, float ws) {
                float d = nb - x0;
                float w = __builtin_amdgcn_exp2f(fmaf(d * d, Cc, ws));
                num = fmaf(w, nb, num);
                den += w;
            };
            acc(A0, Ws2); acc(A1, Ws1); acc(A2, Ws2);
            acc(B0, Ws1);               acc(B2, Ws1);
            acc(C0, Ws2); acc(C1, Ws1); acc(C2, Ws2);
            psum = fmaf(num, __builtin_amdgcn_rcpf(den), psum);
        }
        // ---- pixel 1: center B2, window {A1,A2,A3, B1,B3, C1,C2,C3} ----
        {
            const float x0 = B2;
            float num = x0, den = 1.0f;
            auto acc = [&](float nb, float ws) {
                float d = nb - x0;
                float w = __builtin_amdgcn_exp2f(fmaf(d * d, Cc, ws));
                num = fmaf(w, nb, num);
                den += w;
            };
            acc(A1, Ws2); acc(A2, Ws1); acc(A3, Ws2);
            acc(B1, Ws1);               acc(B3, Ws1);
            acc(C1, Ws2); acc(C2, Ws1); acc(C3, Ws2);
            psum = fmaf(num, __builtin_amdgcn_rcpf(den), psum);
        }

        // ---- rotate window, then issue next prefetch (distance 2) ----
        A0 = B0; A1 = B1; A2 = B2; A3 = B3;
        B0 = C0; B1 = C1; B2 = C2; B3 = C3;
        C0 = P0; C1 = P1; C2 = P2; C3 = P3;
        if (r < 14) {
            LOADROW(r + 3, P0, P1, P2, P3)
        }
    }
#undef LOADROW

    // pool block = 16 cols = 8 lanes (2 cols each); 16 rows already in psum
    psum += __shfl_xor(psum, 1);
    psum += __shfl_xor(psum, 2);
    psum += __shfl_xor(psum, 4);

    if ((t & 7) == 0) {
        const int pc = (ch << 5) + (t >> 3);   // pool col 0..63
        out[(size_t)((b << 6) + pr) * 64 + pc] = psum * (1.0f / 256.0f);
    }
}

extern "C" void kernel_launch(void* const* d_in, const int* in_sizes, int n_in,
                              void* d_out, int out_size, void* d_ws, size_t ws_size,
                              hipStream_t stream) {
    const float* x = (const float*)d_in[0];
    float* out     = (float*)d_out;
    // grid: 16 batches * 64 pool rows * 2 column halves; 256 threads (2 cols x 16 rows each)
    EdgePreserve_kernel<<<dim3(16 * 64 * 2), dim3(256), 0, stream>>>(x, out);
}

// Round 5
// 27.178 us; speedup vs baseline: 1.8752x; 1.2194x over previous
//
#include <hip/hip_runtime.h>

#define IMG_H 1024
#define IMG_W 1024

#define CC  (-0.1803368801111244f)     // -(1/8)*log2(e)
#define WS1 (-2.8853900817779270e-4f)  // log2(exp(-1/5000))
#define WS2 (-5.7707801635558540e-4f)  // log2(exp(-2/5000))

__device__ __forceinline__ float edgew(float u, float v, float ws) {
    float d = u - v;
    return __builtin_amdgcn_exp2f(fmaf(d * d, CC, ws));
}

__global__ __launch_bounds__(512) void EdgePreserve_kernel(const float* __restrict__ x,
                                                           float* __restrict__ out) {
    const int t    = threadIdx.x;
    const int half = t >> 8;            // 0: rows 0-7 of strip, 1: rows 8-15
    const int tt   = t & 255;

    const int bid = blockIdx.x;         // b*64 + pool_row
    const int b   = bid >> 6;
    const int pr  = bid & 63;
    const int r0  = (pr << 4) + (half << 3);
    const int c0  = tt << 2;            // 4 cols per thread

    const float* base = x + (size_t)b * (IMG_H * IMG_W);
    const int cl = (c0 == 0) ? 1 : c0 - 1;                 // reflect left halo col
    const int cr = (c0 + 4 >= IMG_W) ? IMG_W - 2 : c0 + 4; // reflect right halo col

    // rows as named scalars: a=r-1, b=r, k=r+1, p=prefetch(r+3)
    float a0,a1,a2,a3,a4,a5, b0,b1,b2,b3,b4,b5, k0,k1,k2,k3,k4,k5, p0,p1,p2,p3,p4,p5;

#define LOADROW(q, d0,d1,d2,d3,d4,d5) { \
    int _r = r0 + (q); \
    int _rr = (_r < 0) ? -_r : ((_r >= IMG_H) ? (2*IMG_H-2-_r) : _r); \
    const float* _rp = base + _rr * IMG_W; \
    float4 _v = *reinterpret_cast<const float4*>(_rp + c0); \
    d0 = _rp[cl]; d1 = _v.x; d2 = _v.y; d3 = _v.z; d4 = _v.w; d5 = _rp[cr]; }

    LOADROW(-1, a0,a1,a2,a3,a4,a5)
    LOADROW( 0, b0,b1,b2,b3,b4,b5)
    LOADROW( 1, k0,k1,k2,k3,k4,k5)
    LOADROW( 2, p0,p1,p2,p3,p4,p5)

    // edges between rows A and B (will be this iter's A-row weights):
    // pV_c = w(a_c,b_c); pDL_c = w(a_c,b_{c-1}); pDR_c = w(a_c,b_{c+1})
    float pV1 = edgew(a1,b1,WS1), pV2 = edgew(a2,b2,WS1), pV3 = edgew(a3,b3,WS1), pV4 = edgew(a4,b4,WS1);
    float pDL2 = edgew(a2,b1,WS2), pDL3 = edgew(a3,b2,WS2), pDL4 = edgew(a4,b3,WS2), pDL5 = edgew(a5,b4,WS2);
    float pDR0 = edgew(a0,b1,WS2), pDR1 = edgew(a1,b2,WS2), pDR2 = edgew(a2,b3,WS2), pDR3 = edgew(a3,b4,WS2);

    float psum = 0.0f;

    #pragma unroll
    for (int r = 0; r < 8; ++r) {
        // horizontal edges within row B (shared by adjacent pixels)
        float H0 = edgew(b0,b1,WS1), H1 = edgew(b1,b2,WS1), H2 = edgew(b2,b3,WS1),
              H3 = edgew(b3,b4,WS1), H4 = edgew(b4,b5,WS1);
        // edges between rows B and C (used now; reused next iter as A-row weights)
        float V1  = edgew(b1,k1,WS1), V2  = edgew(b2,k2,WS1), V3  = edgew(b3,k3,WS1), V4 = edgew(b4,k4,WS1);
        float DL1 = edgew(b1,k0,WS2), DL2 = edgew(b2,k1,WS2), DL3 = edgew(b3,k2,WS2),
              DL4 = edgew(b4,k3,WS2), DL5 = edgew(b5,k4,WS2);
        float DR0 = edgew(b0,k1,WS2), DR1 = edgew(b1,k2,WS2), DR2 = edgew(b2,k3,WS2),
              DR3 = edgew(b3,k4,WS2), DR4 = edgew(b4,k5,WS2);

#define PIXEL(am,ac,ap, bm,bc,bp, km,kc,kp, wAL,wAC,wAR, wBL,wBR, wCL,wCV,wCR) { \
        float num = bc; \
        num = fmaf(wAL, am, num); num = fmaf(wAC, ac, num); num = fmaf(wAR, ap, num); \
        num = fmaf(wBL, bm, num); num = fmaf(wBR, bp, num); \
        num = fmaf(wCL, km, num); num = fmaf(wCV, kc, num); num = fmaf(wCR, kp, num); \
        float den = 1.0f + (((wAL + wAC) + (wAR + wBL)) + ((wBR + wCL) + (wCV + wCR))); \
        psum = fmaf(num, __builtin_amdgcn_rcpf(den), psum); }

        // pixel c: A-row weights {pDR_{c-1}, pV_c, pDL_{c+1}}, B-row {H_{c-1}, H_c}, C-row {DL_c, V_c, DR_c}
        PIXEL(a0,a1,a2, b0,b1,b2, k0,k1,k2, pDR0,pV1,pDL2, H0,H1, DL1,V1,DR1)
        PIXEL(a1,a2,a3, b1,b2,b3, k1,k2,k3, pDR1,pV2,pDL3, H1,H2, DL2,V2,DR2)
        PIXEL(a2,a3,a4, b2,b3,b4, k2,k3,k4, pDR2,pV3,pDL4, H2,H3, DL3,V3,DR3)
        PIXEL(a3,a4,a5, b3,b4,b5, k3,k4,k5, pDR3,pV4,pDL5, H3,H4, DL4,V4,DR4)
#undef PIXEL

        // rotate rows
        a0=b0;a1=b1;a2=b2;a3=b3;a4=b4;a5=b5;
        b0=k0;b1=k1;b2=k2;b3=k3;b4=k4;b5=k5;
        k0=p0;k1=p1;k2=p2;k3=p3;k4=p4;k5=p5;
        // rotate edge weights: next iter's A-row weights = this iter's B-C edges
        pV1=V1;  pV2=V2;  pV3=V3;  pV4=V4;
        pDL2=DL2;pDL3=DL3;pDL4=DL4;pDL5=DL5;
        pDR0=DR0;pDR1=DR1;pDR2=DR2;pDR3=DR3;
        if (r < 6) { LOADROW(r+3, p0,p1,p2,p3,p4,p5) }
    }
#undef LOADROW

    // pool block = 16 cols = 4 lanes (4 cols each)
    psum += __shfl_xor(psum, 1);
    psum += __shfl_xor(psum, 2);

    // combine the two 8-row halves via LDS
    __shared__ float red[64];
    if (half == 1 && (tt & 3) == 0) red[tt >> 2] = psum;
    __syncthreads();
    if (half == 0 && (tt & 3) == 0) {
        out[(size_t)bid * 64 + (tt >> 2)] = (psum + red[tt >> 2]) * (1.0f / 256.0f);
    }
}

extern "C" void kernel_launch(void* const* d_in, const int* in_sizes, int n_in,
                              void* d_out, int out_size, void* d_ws, size_t ws_size,
                              hipStream_t stream) {
    const float* x = (const float*)d_in[0];
    float* out     = (float*)d_out;
    // grid: 16 batches * 64 pool rows; block: 512 threads (2 row-halves x 256 threads x 4 cols)
    EdgePreserve_kernel<<<dim3(16 * 64), dim3(512), 0, stream>>>(x, out);
}